// Round 27
// baseline (106.699 us; speedup 1.0000x reference)
//
#include <hip/hip_runtime.h>
#include <hip/hip_bf16.h>
#include <stdint.h>
#include <math.h>

typedef __attribute__((ext_vector_type(4))) float f32x4;
typedef _Float16 f16;
typedef __attribute__((ext_vector_type(8))) _Float16 f16x8;
typedef decltype(__builtin_amdgcn_cvt_pkrtz(0.f, 0.f)) pk16;

#define DIM   768
#define NH    12
#define HD    64
#define NB    8
#define SEQ   512
#define SCALE 0.125f

#define GN    161          // grid points per axis (Δ=1/8 over [-10,10])
#define GPTS  (GN * GN)    // 25921

#define MFMA16H __builtin_amdgcn_mfma_f32_16x16x32_f16

// Raw barrier: orders LDS ops (lgkmcnt(0)) but does NOT drain outstanding
// global loads (no vmcnt(0)) -> prefetch stays in flight across the barrier.
#define BARRIER_KEEP_LOADS()                                   \
    do {                                                       \
        asm volatile("s_waitcnt lgkmcnt(0)" ::: "memory");     \
        __builtin_amdgcn_s_barrier();                          \
    } while (0)

// ---------------- prep (fused): f32->f16 converts + 4x W transpose + MLP tables ----------------
struct PrepArgs {
    const float* query; const float* key_value; f16* Xq; f16* Xkv;
    const float* W[4]; f16* WT[4];
    const float* W1; const float* b1; const float* W2;
    f16* W1tab; f16* W2tab; float* gtab32;
};

__global__ void __launch_bounds__(256) k_prep(PrepArgs pa) {
    __shared__ float tt[32][33];
    int g = blockIdx.x, t = threadIdx.x;
    if (g < 3072) {
        const float* in = (g < 1536) ? pa.query : pa.key_value;
        f16* out = (g < 1536) ? pa.Xq : pa.Xkv;
        int i = (g % 1536) * 256 + t;
        const float4* s = reinterpret_cast<const float4*>(in + i * 8);
        float4 f0 = s[0], f1 = s[1];
        union { pk16 h[4]; uint4 v; } o;
        o.h[0] = __builtin_amdgcn_cvt_pkrtz(f0.x, f0.y);
        o.h[1] = __builtin_amdgcn_cvt_pkrtz(f0.z, f0.w);
        o.h[2] = __builtin_amdgcn_cvt_pkrtz(f1.x, f1.y);
        o.h[3] = __builtin_amdgcn_cvt_pkrtz(f1.z, f1.w);
        reinterpret_cast<uint4*>(out)[i] = o.v;
    } else if (g < 5376) {
        int bi = g - 3072;               // 0..2303
        int z = bi / 576, rem = bi % 576;
        int bx = rem % 24, by = rem / 24;
        const float* W = pa.W[z];
        f16* WT = pa.WT[z];
        int n0 = bx * 32, k0 = by * 32;
        int tx = t & 31, ty = t >> 5;    // 32 x 8
#pragma unroll
        for (int j = 0; j < 4; ++j)
            tt[ty + 8 * j][tx] = W[(k0 + ty + 8 * j) * DIM + n0 + tx];
        __syncthreads();
#pragma unroll
        for (int j = 0; j < 4; ++j)
            WT[(n0 + ty + 8 * j) * DIM + k0 + tx] = (f16)tt[tx][ty + 8 * j];
    } else {
        int i = (g - 5376) * 256 + t;    // 0..8703
        if (i < 3072) {
            int lane = i & 63;
            int hi = lane >> 4, m = lane & 15;
            int u = (i >> 6) * 16 + m;
#pragma unroll
            for (int e = 0; e < 8; ++e) {
                float v = 0.f;
                if (hi == 0) {
                    if (e < 6) v = pa.W1[e * DIM + u];
                    else if (e == 6) v = pa.b1[u];
                }
                pa.W1tab[i * 8 + e] = (f16)v;
            }
        } else if (i < 4608) {
            int i2 = i - 3072;
            int j = i2 >> 6, lane = i2 & 63;
            int gq = lane >> 4, h = lane & 15;
#pragma unroll
            for (int e = 0; e < 8; ++e) {
                int u = 32 * j + ((e >> 2) << 4) + (gq << 2) + (e & 3);
                float v = (h < 12) ? pa.W2[u * 12 + h] : 0.f;
                pa.W2tab[i2 * 8 + e] = (f16)v;
            }
        } else {
            int i2 = i - 4608;           // 0..4095
            float x = (i2 + 0.5f) * (1.0f / 256.0f) - 8.0f;
            pa.gtab32[i2] = 0.5f * x * (1.0f + erff(x * 0.70710678f));
        }
    }
}

// ---------------- bias MLP on the 161x161 delta grid: 1-wave blocks (latency-spread) ----------------
// 1621 blocks x 64 threads; each wave processes 16 grid points (same math as before).
__global__ void __launch_bounds__(64) k_grid(const f16x8* __restrict__ W1tab,
                                             const f16x8* __restrict__ W2tab,
                                             const float* __restrict__ b2,
                                             const float* __restrict__ gtab32,
                                             f16* __restrict__ grid16) {
    __shared__ float tab[4096];   // 16 KB gelu LUT
    int t = threadIdx.x, lane = t;
    {
        const uint4* gt = (const uint4*)gtab32;
        uint4* st = (uint4*)tab;
#pragma unroll
        for (int i = 0; i < 16; ++i) st[i * 64 + t] = gt[i * 64 + t];
    }
    int hi = lane >> 4, m = lane & 15;
    int p0 = blockIdx.x * 16;
    int p = p0 + m;
    if (p >= GPTS) p = GPTS - 1;          // clamp (dup compute, guarded store)
    int gy = p / GN, gx = p - gy * GN;
    float dx = gx * 0.125f - 10.0f;
    float dy = gy * 0.125f - 10.0f;

    union { f16x8 v; pk16 h2[4]; } rf;
    { f16x8 zz = {}; rf.v = zz; }
    if (hi == 0) {
        rf.h2[0] = __builtin_amdgcn_cvt_pkrtz(dx, dy);
        rf.h2[1] = __builtin_amdgcn_cvt_pkrtz(fabsf(dx), fabsf(dy));
        rf.h2[2] = __builtin_amdgcn_cvt_pkrtz(dx * dx, dy * dy);
        rf.h2[3] = __builtin_amdgcn_cvt_pkrtz(1.0f, 0.0f);
    }

    float b2h = (m < 12) ? b2[m] : 0.f;
    f32x4 acc = {b2h, b2h, b2h, b2h};
    const f32x4 zero = {};
    const f16x8* w1p = W1tab + lane;
    const f16x8* w2p = W2tab + lane;
    __syncthreads();

#pragma unroll 2
    for (int j = 0; j < 24; ++j) {
        f16x8 a0  = w1p[(2 * j) * 64];
        f16x8 a1  = w1p[(2 * j + 1) * 64];
        f16x8 w2v = w2p[j * 64];
        f32x4 pre0 = MFMA16H(a0, rf.v, zero, 0, 0, 0);
        f32x4 pre1 = MFMA16H(a1, rf.v, zero, 0, 0, 0);
        float s0[4], s1[4];
#pragma unroll
        for (int e = 0; e < 4; ++e) {
            float x0 = pre0[e];
            float xi0 = __builtin_amdgcn_fmed3f(__builtin_fmaf(x0, 256.f, 2048.f), 0.f, 4095.f);
            float g0 = tab[(int)xi0];
            s0[e] = (x0 > 8.f) ? x0 : g0;
            float x1 = pre1[e];
            float xi1 = __builtin_amdgcn_fmed3f(__builtin_fmaf(x1, 256.f, 2048.f), 0.f, 4095.f);
            float g1 = tab[(int)xi1];
            s1[e] = (x1 > 8.f) ? x1 : g1;
        }
        union { f16x8 v; pk16 h2[4]; } pav;
        pav.h2[0] = __builtin_amdgcn_cvt_pkrtz(s0[0], s0[1]);
        pav.h2[1] = __builtin_amdgcn_cvt_pkrtz(s0[2], s0[3]);
        pav.h2[2] = __builtin_amdgcn_cvt_pkrtz(s1[0], s1[1]);
        pav.h2[3] = __builtin_amdgcn_cvt_pkrtz(s1[2], s1[3]);
        acc = MFMA16H(pav.v, w2v, acc, 0, 0, 0);
    }
    // D: col=m (head for m<12; duplicated-clamp lanes write only via guard), row=hi*4+r = point-local
    if (m < 12) {
#pragma unroll
        for (int r = 0; r < 4; ++r) {
            int pr = p0 + hi * 4 + r;
            if (pr < GPTS) grid16[pr * 16 + m] = (f16)acc[r];
        }
    }
}

// ---------------- fused QKV GEMM (64x64, depth-3 prefetch, loads live across barriers) ----------------
struct MQArgs {
    const float* qc; const float* kc;
    const f16* grid16; f16* bias16;
    const f16* Xq; const f16* Xkv;
    const f16* WqT; const f16* WkT; const f16* WvT;
    const float* bq; const float* bk; const float* bv;
    f16* q_ws; f16* k_ws; f16* v_t;
};

__global__ void __launch_bounds__(256) k_mq9(MQArgs a) {
    __shared__ uint4 lds[1024];   // 16 KB (GEMM dbuf)
    int bid = blockIdx.x, t = threadIdx.x;
    int lane = t & 63, w = t >> 6;
    int hi = lane >> 4, lm = lane & 15;
    int xcd = bid & 7, slot = bid >> 3;

    if (slot >= 128) {
        int lid = xcd * 288 + (slot - 128);    // 0..2303
        int m_group = lid / 36;
        int within = lid - m_group * 36;
        int z = within / 12;
        int n_tile = within - z * 12;
        int m0 = m_group * 64, n0 = n_tile * 64;
        const f16* X = (z == 0) ? a.Xq : a.Xkv;
        const f16* Wt = (z == 0) ? a.WqT : (z == 1) ? a.WkT : a.WvT;
        const float* bias = (z == 0) ? a.bq : (z == 1) ? a.bk : a.bv;
        f16* out = (z == 0) ? a.q_ws : (z == 1) ? a.k_ws : a.v_t;

        int wr = w >> 1, wc = w & 1;
        int srow = t >> 2, sslot = t & 3;      // 64 rows x 4 uint4-slots
        const f16* Ag = X + (m0 + srow) * DIM + sslot * 8;
        const f16* Bg = Wt + (n0 + srow) * DIM + sslot * 8;
        int wi = srow * 4 + (sslot ^ ((srow >> 1) & 3));

        int aidx[2], bidx[2];
#pragma unroll
        for (int i = 0; i < 2; ++i) {
            int ar = wr * 32 + i * 16 + lm;
            aidx[i] = ar * 4 + (hi ^ ((ar >> 1) & 3));
            int br = wc * 32 + i * 16 + lm;
            bidx[i] = 256 + br * 4 + (hi ^ ((br >> 1) & 3));
        }

        f32x4 acc[2][2] = {};
        {
            uint4 a0 = *(const uint4*)(Ag);
            uint4 b0 = *(const uint4*)(Bg);
            lds[wi] = a0;
            lds[256 + wi] = b0;
        }
        uint4 sA1 = *(const uint4*)(Ag + 32);   // tile1 (odd set)
        uint4 sB1 = *(const uint4*)(Bg + 32);
        uint4 sA0 = *(const uint4*)(Ag + 64);   // tile2 (even set)
        uint4 sB0 = *(const uint4*)(Bg + 64);
        BARRIER_KEEP_LOADS();                   // tile1/2 loads stay in flight

#define MQ_COMPUTE(kt)                                                        \
        {                                                                     \
            int bo = ((kt) & 1) << 9;                                         \
            f16x8 af0 = *(const f16x8*)&lds[bo + aidx[0]];                    \
            f16x8 af1 = *(const f16x8*)&lds[bo + aidx[1]];                    \
            f16x8 bf0 = *(const f16x8*)&lds[bo + bidx[0]];                    \
            f16x8 bf1 = *(const f16x8*)&lds[bo + bidx[1]];                    \
            acc[0][0] = MFMA16H(af0, bf0, acc[0][0], 0, 0, 0);                \
            acc[0][1] = MFMA16H(af0, bf1, acc[0][1], 0, 0, 0);                \
            acc[1][0] = MFMA16H(af1, bf0, acc[1][0], 0, 0, 0);                \
            acc[1][1] = MFMA16H(af1, bf1, acc[1][1], 0, 0, 0);                \
        }

        for (int kp = 0; kp < 12; ++kp) {
            int kt = 2 * kp;
            MQ_COMPUTE(kt)
            {
                int bo2 = (((kt) & 1) << 9) ^ 512;
                lds[bo2 + wi] = sA1;             // compiler waits only set1's loads
                lds[bo2 + 256 + wi] = sB1;
                if (kt + 3 < 24) {
                    sA1 = *(const uint4*)(Ag + (kt + 3) * 32);
                    sB1 = *(const uint4*)(Bg + (kt + 3) * 32);
                }
                BARRIER_KEEP_LOADS();            // set0/set1 prefetch stays in flight
            }
            kt = 2 * kp + 1;
            MQ_COMPUTE(kt)
            if (kt < 23) {
                int bo2 = (((kt) & 1) << 9) ^ 512;
                lds[bo2 + wi] = sA0;
                lds[bo2 + 256 + wi] = sB0;
                if (kt + 3 < 24) {
                    sA0 = *(const uint4*)(Ag + (kt + 3) * 32);
                    sB0 = *(const uint4*)(Bg + (kt + 3) * 32);
                }
                BARRIER_KEEP_LOADS();
            }
        }
#undef MQ_COMPUTE

#pragma unroll
        for (int mi = 0; mi < 2; ++mi)
#pragma unroll
            for (int ni = 0; ni < 2; ++ni) {
                int n = n0 + wc * 32 + ni * 16 + lm;
                float bn = bias[n];
                int h = n >> 6, d = n & 63;
                int mbase = m0 + wr * 32 + mi * 16 + hi * 4;
                int bb = mbase >> 9, l0 = mbase & 511;
                if (z == 2) {
                    union { pk16 h2[2]; uint2 u2; } o;
                    o.h2[0] = __builtin_amdgcn_cvt_pkrtz(acc[mi][ni][0] + bn, acc[mi][ni][1] + bn);
                    o.h2[1] = __builtin_amdgcn_cvt_pkrtz(acc[mi][ni][2] + bn, acc[mi][ni][3] + bn);
                    *reinterpret_cast<uint2*>(out + (((bb * NH + h) * HD) + d) * SEQ + l0) = o.u2;
                } else {
#pragma unroll
                    for (int r = 0; r < 4; ++r)
                        out[(((bb * NH + h) * SEQ) + l0 + r) * HD + d] = (f16)(acc[mi][ni][r] + bn);
                }
            }
    } else {
        // ---------- interp role: bilinear bias, 1 pair per thread ----------
        int p = (xcd * 128 + slot) * 256 + t;
        int qi = p >> 9, ki = p & 511;
        float dx = a.qc[2 * qi] - a.kc[2 * ki];
        float dy = a.qc[2 * qi + 1] - a.kc[2 * ki + 1];
        float fxf = __builtin_amdgcn_fmed3f(__builtin_fmaf(dx, 8.f, 80.f), 0.f, 159.9999f);
        float fyf = __builtin_amdgcn_fmed3f(__builtin_fmaf(dy, 8.f, 80.f), 0.f, 159.9999f);
        int ix = (int)fxf, iy = (int)fyf;
        float fx = fxf - (float)ix, fy = fyf - (float)iy;
        const f16* c00 = a.grid16 + (iy * GN + ix) * 16;
        f16x8 g00 = *(const f16x8*)(c00);
        f16x8 g00b = *(const f16x8*)(c00 + 8);
        f16x8 g01 = *(const f16x8*)(c00 + 16);
        f16x8 g01b = *(const f16x8*)(c00 + 24);
        f16x8 g10 = *(const f16x8*)(c00 + GN * 16);
        f16x8 g10b = *(const f16x8*)(c00 + GN * 16 + 8);
        f16x8 g11 = *(const f16x8*)(c00 + GN * 16 + 16);
        f16x8 g11b = *(const f16x8*)(c00 + GN * 16 + 24);
        float o[12];
#pragma unroll
        for (int h = 0; h < 12; ++h) {
            float v00 = (float)(h < 8 ? g00[h] : g00b[h - 8]);
            float v01 = (float)(h < 8 ? g01[h] : g01b[h - 8]);
            float v10 = (float)(h < 8 ? g10[h] : g10b[h - 8]);
            float v11 = (float)(h < 8 ? g11[h] : g11b[h - 8]);
            float v0 = __builtin_fmaf(fx, v01 - v00, v00);
            float v1 = __builtin_fmaf(fx, v11 - v10, v10);
            o[h] = __builtin_fmaf(fy, v1 - v0, v0);
        }
#pragma unroll
        for (int h = 0; h < 12; ++h)
            a.bias16[h * (SEQ * SEQ) + p] = (f16)o[h];
    }
}

// ---------------- O-proj GEMM: 64x64 tile, depth-3 prefetch, raw barriers ----------------
__global__ void __launch_bounds__(256) k_gemmO3(const f16* __restrict__ X,
                                                const f16* __restrict__ WT,
                                                const float* __restrict__ bias,
                                                float* __restrict__ out) {
    __shared__ uint4 lds[1024];
    int bid = blockIdx.x, t = threadIdx.x;
    int lane = t & 63, w = t >> 6;
    int hi = lane >> 4, lm = lane & 15;
    int xcd = bid & 7, slot = bid >> 3;
    int lid = xcd * 96 + slot;
    int m_group = lid / 12, n_tile = lid % 12;
    int m0 = m_group * 64, n0 = n_tile * 64;

    int wr = w >> 1, wc = w & 1;
    int srow = t >> 2, sslot = t & 3;
    const f16* Ag = X + (m0 + srow) * DIM + sslot * 8;
    const f16* Bg = WT + (n0 + srow) * DIM + sslot * 8;
    int wi = srow * 4 + (sslot ^ ((srow >> 1) & 3));

    int aidx[2], bidx[2];
#pragma unroll
    for (int i = 0; i < 2; ++i) {
        int ar = wr * 32 + i * 16 + lm;
        aidx[i] = ar * 4 + (hi ^ ((ar >> 1) & 3));
        int br = wc * 32 + i * 16 + lm;
        bidx[i] = 256 + br * 4 + (hi ^ ((br >> 1) & 3));
    }

    f32x4 acc[2][2] = {};
    {
        uint4 a0 = *(const uint4*)(Ag);
        uint4 b0 = *(const uint4*)(Bg);
        lds[wi] = a0;
        lds[256 + wi] = b0;
    }
    uint4 sA1 = *(const uint4*)(Ag + 32);
    uint4 sB1 = *(const uint4*)(Bg + 32);
    uint4 sA0 = *(const uint4*)(Ag + 64);
    uint4 sB0 = *(const uint4*)(Bg + 64);
    BARRIER_KEEP_LOADS();

#define GO_COMPUTE(kt)                                                        \
    {                                                                         \
        int bo = ((kt) & 1) << 9;                                             \
        f16x8 af0 = *(const f16x8*)&lds[bo + aidx[0]];                        \
        f16x8 af1 = *(const f16x8*)&lds[bo + aidx[1]];                        \
        f16x8 bf0 = *(const f16x8*)&lds[bo + bidx[0]];                        \
        f16x8 bf1 = *(const f16x8*)&lds[bo + bidx[1]];                        \
        acc[0][0] = MFMA16H(af0, bf0, acc[0][0], 0, 0, 0);                    \
        acc[0][1] = MFMA16H(af0, bf1, acc[0][1], 0, 0, 0);                    \
        acc[1][0] = MFMA16H(af1, bf0, acc[1][0], 0, 0, 0);                    \
        acc[1][1] = MFMA16H(af1, bf1, acc[1][1], 0, 0, 0);                    \
    }

    for (int kp = 0; kp < 12; ++kp) {
        int kt = 2 * kp;
        GO_COMPUTE(kt)
        {
            int bo2 = (((kt) & 1) << 9) ^ 512;
            lds[bo2 + wi] = sA1;
            lds[bo2 + 256 + wi] = sB1;
            if (kt + 3 < 24) {
                sA1 = *(const uint4*)(Ag + (kt + 3) * 32);
                sB1 = *(const uint4*)(Bg + (kt + 3) * 32);
            }
            BARRIER_KEEP_LOADS();
        }
        kt = 2 * kp + 1;
        GO_COMPUTE(kt)
        if (kt < 23) {
            int bo2 = (((kt) & 1) << 9) ^ 512;
            lds[bo2 + wi] = sA0;
            lds[bo2 + 256 + wi] = sB0;
            if (kt + 3 < 24) {
                sA0 = *(const uint4*)(Ag + (kt + 3) * 32);
                sB0 = *(const uint4*)(Bg + (kt + 3) * 32);
            }
            BARRIER_KEEP_LOADS();
        }
    }
#undef GO_COMPUTE

#pragma unroll
    for (int mi = 0; mi < 2; ++mi)
#pragma unroll
        for (int ni = 0; ni < 2; ++ni) {
            int n = n0 + wc * 32 + ni * 16 + lm;
            float bn = bias[n];
#pragma unroll
            for (int r = 0; r < 4; ++r) {
                int m = m0 + wr * 32 + mi * 16 + hi * 4 + r;
                out[m * DIM + n] = acc[mi][ni][r] + bn;
            }
        }
}

// ---------------- attention: bias pre-staged to LDS, vectorized softmax scans ----------------
__global__ void __launch_bounds__(256) k_attn8(const f16* __restrict__ q_ws,
                                               const f16* __restrict__ k_ws,
                                               const f16* __restrict__ v_t,
                                               const f16* __restrict__ bias16,
                                               f16* __restrict__ attn_out) {
    __shared__ __align__(16) unsigned short sm16[32 * 520];  // f16 logits [32][520]
    __shared__ float inv32[32];
    int bid = blockIdx.x;
    int xcd = bid & 7, slot = bid >> 3;
    int G = xcd * 12 + (slot >> 4);
    int h = G >> 3, b = G & 7;
    int qt = slot & 15;
    int q0 = qt * 32;
    int t = threadIdx.x, lane = t & 63, w = t >> 6;
    int lrow = lane & 15, hi = lane >> 4;
    int bh = b * NH + h;
    const f16* Q = q_ws + (bh * SEQ + q0) * HD;
    const f16* K = k_ws + bh * SEQ * HD;
    const f16* Bias = bias16 + (h * SEQ + q0) * SEQ;

    // pre-stage bias slice [32][512] into sm16 with coalesced uint4 loads
#pragma unroll
    for (int i = 0; i < 8; ++i) {
        int f = i * 256 + t;
        int row = f >> 6, col8 = f & 63;
        uint4 v = *(const uint4*)&Bias[row * SEQ + col8 * 8];
        *(uint4*)&sm16[row * 520 + col8 * 8] = v;
    }

    f16x8 aq[2][2];
#pragma unroll
    for (int rt = 0; rt < 2; ++rt)
#pragma unroll
        for (int ds = 0; ds < 2; ++ds) {
            f16x8 v = *(const f16x8*)(Q + (rt * 16 + lrow) * HD + ds * 32 + hi * 8);
            aq[rt][ds] = v * (f16)SCALE;   // exact (pow2)
        }
    __syncthreads();

    // phase A: S = (Q*SCALE)K^T + bias(LDS) -> f16 LDS
#pragma unroll
    for (int ct = 0; ct < 8; ++ct) {
        f32x4 acc0 = {}, acc1 = {};
        int kk = w * 128 + ct * 16 + lrow;
#pragma unroll
        for (int ds = 0; ds < 2; ++ds) {
            f16x8 bk = *(const f16x8*)(K + kk * HD + ds * 32 + hi * 8);
            acc0 = MFMA16H(aq[0][ds], bk, acc0, 0, 0, 0);
            acc1 = MFMA16H(aq[1][ds], bk, acc1, 0, 0, 0);
        }
#pragma unroll
        for (int r = 0; r < 4; ++r) {
            int row0 = hi * 4 + r;
            float b0v = (float)*(const f16*)&sm16[row0 * 520 + kk];
            sm16[row0 * 520 + kk] = (unsigned short)__builtin_bit_cast(unsigned short,
                (f16)(acc0[r] + b0v));
            int row1 = 16 + hi * 4 + r;
            float b1v = (float)*(const f16*)&sm16[row1 * 520 + kk];
            sm16[row1 * 520 + kk] = (unsigned short)__builtin_bit_cast(unsigned short,
                (f16)(acc1[r] + b1v));
        }
    }
    __syncthreads();

    // phase B: row softmax, 8 lanes/row, uint4 (8 f16) per scan step
    {
        int row = t >> 3, seg = t & 7;
        int base = row * 520 + seg * 8;
        float mx = -1e30f;
#pragma unroll
        for (int j = 0; j < 8; ++j) {
            union { uint4 u; f16 hh[8]; } cv;
            cv.u = *(const uint4*)&sm16[base + 64 * j];
            float m0 = fmaxf((float)cv.hh[0], (float)cv.hh[1]);
            float m1 = fmaxf((float)cv.hh[2], (float)cv.hh[3]);
            float m2 = fmaxf((float)cv.hh[4], (float)cv.hh[5]);
            float m3 = fmaxf((float)cv.hh[6], (float)cv.hh[7]);
            mx = fmaxf(mx, fmaxf(fmaxf(m0, m1), fmaxf(m2, m3)));
        }
        mx = fmaxf(mx, __shfl_xor(mx, 1));
        mx = fmaxf(mx, __shfl_xor(mx, 2));
        mx = fmaxf(mx, __shfl_xor(mx, 4));
        float s = 0.f;
#pragma unroll
        for (int j = 0; j < 8; ++j) {
            union { uint4 u; f16 hh[8]; } cv;
            cv.u = *(const uint4*)&sm16[base + 64 * j];
            float p[8];
#pragma unroll
            for (int e = 0; e < 8; ++e) {
                p[e] = __builtin_amdgcn_exp2f(((float)cv.hh[e] - mx) * 1.442695041f);
                s += p[e];
            }
            union { pk16 hh[4]; uint4 u; } o;
            o.hh[0] = __builtin_amdgcn_cvt_pkrtz(p[0], p[1]);
            o.hh[1] = __builtin_amdgcn_cvt_pkrtz(p[2], p[3]);
            o.hh[2] = __builtin_amdgcn_cvt_pkrtz(p[4], p[5]);
            o.hh[3] = __builtin_amdgcn_cvt_pkrtz(p[6], p[7]);
            *(uint4*)&sm16[base + 64 * j] = o.u;
        }
        s += __shfl_xor(s, 1);
        s += __shfl_xor(s, 2);
        s += __shfl_xor(s, 4);
        if (seg == 0) inv32[row] = 1.0f / s;
    }
    __syncthreads();

    // phase C: O = P V
    const f16* Vt = v_t + bh * HD * SEQ + (w * 16 + lrow) * SEQ;
    f32x4 oacc0 = {}, oacc1 = {};
    for (int kt = 0; kt < 16; ++kt) {
        f16x8 bv = *(const f16x8*)(Vt + kt * 32 + hi * 8);
        f16x8 pa0 = *(const f16x8*)&sm16[lrow * 520 + kt * 32 + hi * 8];
        f16x8 pa1 = *(const f16x8*)&sm16[(16 + lrow) * 520 + kt * 32 + hi * 8];
        oacc0 = MFMA16H(pa0, bv, oacc0, 0, 0, 0);
        oacc1 = MFMA16H(pa1, bv, oacc1, 0, 0, 0);
    }
#pragma unroll
    for (int r = 0; r < 4; ++r) {
        int row0 = hi * 4 + r;
        float v0 = oacc0[r] * inv32[row0];
        attn_out[(b * SEQ + q0 + row0) * DIM + h * HD + w * 16 + lrow] = (f16)v0;
        int row1 = 16 + hi * 4 + r;
        float v1 = oacc1[r] * inv32[row1];
        attn_out[(b * SEQ + q0 + row1) * DIM + h * HD + w * 16 + lrow] = (f16)v1;
    }
}

extern "C" void kernel_launch(void* const* d_in, const int* in_sizes, int n_in,
                              void* d_out, int out_size, void* d_ws, size_t ws_size,
                              hipStream_t stream) {
    const float* query     = (const float*)d_in[0];
    const float* key_value = (const float*)d_in[1];
    const float* qc        = (const float*)d_in[2];
    const float* kc        = (const float*)d_in[3];
    const float* Wq        = (const float*)d_in[4];
    const float* bq        = (const float*)d_in[5];
    const float* Wk        = (const float*)d_in[6];
    const float* bk        = (const float*)d_in[7];
    const float* Wv        = (const float*)d_in[8];
    const float* bv        = (const float*)d_in[9];
    const float* Wo        = (const float*)d_in[10];
    const float* bo        = (const float*)d_in[11];
    const float* W1        = (const float*)d_in[12];
    const float* b1        = (const float*)d_in[13];
    const float* W2        = (const float*)d_in[14];
    const float* b2        = (const float*)d_in[15];

    char* ws = (char*)d_ws;
    f16* Xq   = (f16*)(ws + 0);          // reused as attn_out
    f16* Xkv  = (f16*)(ws + 6291456);
    f16* WqT  = (f16*)(ws + 12582912);
    f16* WkT  = (f16*)(ws + 13762560);
    f16* WvT  = (f16*)(ws + 14942208);
    f16* WoT  = (f16*)(ws + 16121856);
    f16* q_ws = (f16*)(ws + 17301504);
    f16* k_ws = (f16*)(ws + 23592960);
    f16* v_t  = (f16*)(ws + 29884416);   // V written directly transposed [b,h,d,l]
    f16* bias16   = (f16*)(ws + 36175872); // 6291456 B
    f16* W1tab    = (f16*)(ws + 42467328);
    f16* W2tab    = (f16*)(ws + 42516480);
    float* gtab32 = (float*)(ws + 42541056); // 16384 B
    f16* grid16   = (f16*)(ws + 42557440);   // 829472 B
    f16* attn_out = Xq;   // Xq dead after Q projection

    PrepArgs pa;
    pa.query = query; pa.key_value = key_value; pa.Xq = Xq; pa.Xkv = Xkv;
    pa.W[0] = Wq; pa.W[1] = Wk; pa.W[2] = Wv; pa.W[3] = Wo;
    pa.WT[0] = WqT; pa.WT[1] = WkT; pa.WT[2] = WvT; pa.WT[3] = WoT;
    pa.W1 = W1; pa.b1 = b1; pa.W2 = W2;
    pa.W1tab = W1tab; pa.W2tab = W2tab; pa.gtab32 = gtab32;
    k_prep<<<dim3(5410), dim3(256), 0, stream>>>(pa);

    k_grid<<<dim3((GPTS + 15) / 16), dim3(64), 0, stream>>>((const f16x8*)W1tab, (const f16x8*)W2tab,
                                                            b2, gtab32, grid16);

    MQArgs mq;
    mq.qc = qc; mq.kc = kc;
    mq.grid16 = grid16; mq.bias16 = bias16;
    mq.Xq = Xq; mq.Xkv = Xkv;
    mq.WqT = WqT; mq.WkT = WkT; mq.WvT = WvT;
    mq.bq = bq; mq.bk = bk; mq.bv = bv;
    mq.q_ws = q_ws; mq.k_ws = k_ws; mq.v_t = v_t;
    k_mq9<<<dim3(3328), dim3(256), 0, stream>>>(mq);

    k_attn8<<<dim3(1536), dim3(256), 0, stream>>>(q_ws, k_ws, v_t, bias16, attn_out);
    k_gemmO3<<<dim3(768), dim3(256), 0, stream>>>(attn_out, WoT, bo, (float*)d_out);
}

// Round 28
// 104.611 us; speedup vs baseline: 1.0200x; 1.0200x over previous
//
#include <hip/hip_runtime.h>
#include <hip/hip_bf16.h>
#include <stdint.h>
#include <math.h>

typedef __attribute__((ext_vector_type(4))) float f32x4;
typedef _Float16 f16;
typedef __attribute__((ext_vector_type(8))) _Float16 f16x8;
typedef decltype(__builtin_amdgcn_cvt_pkrtz(0.f, 0.f)) pk16;

#define DIM   768
#define NH    12
#define HD    64
#define NB    8
#define SEQ   512
#define SCALE 0.125f

#define GN    161          // grid points per axis (Δ=1/8 over [-10,10])
#define GPTS  (GN * GN)    // 25921

#define MFMA16H __builtin_amdgcn_mfma_f32_16x16x32_f16

// Raw barrier: orders LDS ops (lgkmcnt(0)) but does NOT drain outstanding
// global loads (no vmcnt(0)) -> prefetch stays in flight across the barrier.
#define BARRIER_KEEP_LOADS()                                   \
    do {                                                       \
        asm volatile("s_waitcnt lgkmcnt(0)" ::: "memory");     \
        __builtin_amdgcn_s_barrier();                          \
    } while (0)

// ---------------- prep (fused): f32->f16 converts + 4x W transpose + MLP tables ----------------
struct PrepArgs {
    const float* query; const float* key_value; f16* Xq; f16* Xkv;
    const float* W[4]; f16* WT[4];
    const float* W1; const float* b1; const float* W2;
    f16* W1tab; f16* W2tab; float* gtab32;
};

__global__ void __launch_bounds__(256) k_prep(PrepArgs pa) {
    __shared__ float tt[32][33];
    int g = blockIdx.x, t = threadIdx.x;
    if (g < 3072) {
        const float* in = (g < 1536) ? pa.query : pa.key_value;
        f16* out = (g < 1536) ? pa.Xq : pa.Xkv;
        int i = (g % 1536) * 256 + t;
        const float4* s = reinterpret_cast<const float4*>(in + i * 8);
        float4 f0 = s[0], f1 = s[1];
        union { pk16 h[4]; uint4 v; } o;
        o.h[0] = __builtin_amdgcn_cvt_pkrtz(f0.x, f0.y);
        o.h[1] = __builtin_amdgcn_cvt_pkrtz(f0.z, f0.w);
        o.h[2] = __builtin_amdgcn_cvt_pkrtz(f1.x, f1.y);
        o.h[3] = __builtin_amdgcn_cvt_pkrtz(f1.z, f1.w);
        reinterpret_cast<uint4*>(out)[i] = o.v;
    } else if (g < 5376) {
        int bi = g - 3072;               // 0..2303
        int z = bi / 576, rem = bi % 576;
        int bx = rem % 24, by = rem / 24;
        const float* W = pa.W[z];
        f16* WT = pa.WT[z];
        int n0 = bx * 32, k0 = by * 32;
        int tx = t & 31, ty = t >> 5;    // 32 x 8
#pragma unroll
        for (int j = 0; j < 4; ++j)
            tt[ty + 8 * j][tx] = W[(k0 + ty + 8 * j) * DIM + n0 + tx];
        __syncthreads();
#pragma unroll
        for (int j = 0; j < 4; ++j)
            WT[(n0 + ty + 8 * j) * DIM + k0 + tx] = (f16)tt[tx][ty + 8 * j];
    } else {
        int i = (g - 5376) * 256 + t;    // 0..8703
        if (i < 3072) {
            int lane = i & 63;
            int hi = lane >> 4, m = lane & 15;
            int u = (i >> 6) * 16 + m;
#pragma unroll
            for (int e = 0; e < 8; ++e) {
                float v = 0.f;
                if (hi == 0) {
                    if (e < 6) v = pa.W1[e * DIM + u];
                    else if (e == 6) v = pa.b1[u];
                }
                pa.W1tab[i * 8 + e] = (f16)v;
            }
        } else if (i < 4608) {
            int i2 = i - 3072;
            int j = i2 >> 6, lane = i2 & 63;
            int gq = lane >> 4, h = lane & 15;
#pragma unroll
            for (int e = 0; e < 8; ++e) {
                int u = 32 * j + ((e >> 2) << 4) + (gq << 2) + (e & 3);
                float v = (h < 12) ? pa.W2[u * 12 + h] : 0.f;
                pa.W2tab[i2 * 8 + e] = (f16)v;
            }
        } else {
            int i2 = i - 4608;           // 0..4095
            float x = (i2 + 0.5f) * (1.0f / 256.0f) - 8.0f;
            pa.gtab32[i2] = 0.5f * x * (1.0f + erff(x * 0.70710678f));
        }
    }
}

// ---------------- bias MLP evaluated on the 161x161 delta grid ----------------
__global__ void __launch_bounds__(256) k_grid(const f16x8* __restrict__ W1tab,
                                              const f16x8* __restrict__ W2tab,
                                              const float* __restrict__ b2,
                                              const float* __restrict__ gtab32,
                                              f16* __restrict__ grid16) {
    __shared__ float tab[4096];   // 16 KB gelu LUT
    int t = threadIdx.x, lane = t & 63, w = t >> 6;
    {
        const uint4* gt = (const uint4*)gtab32;
        uint4* st = (uint4*)tab;
#pragma unroll
        for (int i = 0; i < 4; ++i) st[i * 256 + t] = gt[i * 256 + t];
    }
    int hi = lane >> 4, m = lane & 15;
    int p0 = blockIdx.x * 64 + w * 16;
    int p = p0 + m;
    int gy = p / GN, gx = p - gy * GN;
    float dx = gx * 0.125f - 10.0f;
    float dy = gy * 0.125f - 10.0f;

    union { f16x8 v; pk16 h2[4]; } rf;
    { f16x8 zz = {}; rf.v = zz; }
    if (hi == 0) {
        rf.h2[0] = __builtin_amdgcn_cvt_pkrtz(dx, dy);
        rf.h2[1] = __builtin_amdgcn_cvt_pkrtz(fabsf(dx), fabsf(dy));
        rf.h2[2] = __builtin_amdgcn_cvt_pkrtz(dx * dx, dy * dy);
        rf.h2[3] = __builtin_amdgcn_cvt_pkrtz(1.0f, 0.0f);
    }

    float b2h = (m < 12) ? b2[m] : 0.f;
    f32x4 acc = {b2h, b2h, b2h, b2h};
    const f32x4 zero = {};
    const f16x8* w1p = W1tab + lane;
    const f16x8* w2p = W2tab + lane;
    __syncthreads();

#pragma unroll 2
    for (int j = 0; j < 24; ++j) {
        f16x8 a0  = w1p[(2 * j) * 64];
        f16x8 a1  = w1p[(2 * j + 1) * 64];
        f16x8 w2v = w2p[j * 64];
        f32x4 pre0 = MFMA16H(a0, rf.v, zero, 0, 0, 0);
        f32x4 pre1 = MFMA16H(a1, rf.v, zero, 0, 0, 0);
        float s0[4], s1[4];
#pragma unroll
        for (int e = 0; e < 4; ++e) {
            float x0 = pre0[e];
            float xi0 = __builtin_amdgcn_fmed3f(__builtin_fmaf(x0, 256.f, 2048.f), 0.f, 4095.f);
            float g0 = tab[(int)xi0];
            s0[e] = (x0 > 8.f) ? x0 : g0;
            float x1 = pre1[e];
            float xi1 = __builtin_amdgcn_fmed3f(__builtin_fmaf(x1, 256.f, 2048.f), 0.f, 4095.f);
            float g1 = tab[(int)xi1];
            s1[e] = (x1 > 8.f) ? x1 : g1;
        }
        union { f16x8 v; pk16 h2[4]; } pav;
        pav.h2[0] = __builtin_amdgcn_cvt_pkrtz(s0[0], s0[1]);
        pav.h2[1] = __builtin_amdgcn_cvt_pkrtz(s0[2], s0[3]);
        pav.h2[2] = __builtin_amdgcn_cvt_pkrtz(s1[0], s1[1]);
        pav.h2[3] = __builtin_amdgcn_cvt_pkrtz(s1[2], s1[3]);
        acc = MFMA16H(pav.v, w2v, acc, 0, 0, 0);
    }
    if (m < 12) {
#pragma unroll
        for (int r = 0; r < 4; ++r) {
            int pr = p0 + hi * 4 + r;
            if (pr < GPTS) grid16[pr * 16 + m] = (f16)acc[r];
        }
    }
}

// ---------------- fused QKV GEMM (64x64, depth-3 prefetch, loads live across barriers) ----------------
struct MQArgs {
    const float* qc; const float* kc;
    const f16* grid16; f16* bias16;
    const f16* Xq; const f16* Xkv;
    const f16* WqT; const f16* WkT; const f16* WvT;
    const float* bq; const float* bk; const float* bv;
    f16* q_ws; f16* k_ws; f16* v_t;
};

__global__ void __launch_bounds__(256) k_mq9(MQArgs a) {
    __shared__ uint4 lds[1024];   // 16 KB (GEMM dbuf)
    int bid = blockIdx.x, t = threadIdx.x;
    int lane = t & 63, w = t >> 6;
    int hi = lane >> 4, lm = lane & 15;
    int xcd = bid & 7, slot = bid >> 3;

    if (slot >= 128) {
        int lid = xcd * 288 + (slot - 128);    // 0..2303
        int m_group = lid / 36;
        int within = lid - m_group * 36;
        int z = within / 12;
        int n_tile = within - z * 12;
        int m0 = m_group * 64, n0 = n_tile * 64;
        const f16* X = (z == 0) ? a.Xq : a.Xkv;
        const f16* Wt = (z == 0) ? a.WqT : (z == 1) ? a.WkT : a.WvT;
        const float* bias = (z == 0) ? a.bq : (z == 1) ? a.bk : a.bv;
        f16* out = (z == 0) ? a.q_ws : (z == 1) ? a.k_ws : a.v_t;

        int wr = w >> 1, wc = w & 1;
        int srow = t >> 2, sslot = t & 3;      // 64 rows x 4 uint4-slots
        const f16* Ag = X + (m0 + srow) * DIM + sslot * 8;
        const f16* Bg = Wt + (n0 + srow) * DIM + sslot * 8;
        int wi = srow * 4 + (sslot ^ ((srow >> 1) & 3));

        int aidx[2], bidx[2];
#pragma unroll
        for (int i = 0; i < 2; ++i) {
            int ar = wr * 32 + i * 16 + lm;
            aidx[i] = ar * 4 + (hi ^ ((ar >> 1) & 3));
            int br = wc * 32 + i * 16 + lm;
            bidx[i] = 256 + br * 4 + (hi ^ ((br >> 1) & 3));
        }

        f32x4 acc[2][2] = {};
        {
            uint4 a0 = *(const uint4*)(Ag);
            uint4 b0 = *(const uint4*)(Bg);
            lds[wi] = a0;
            lds[256 + wi] = b0;
        }
        uint4 sA1 = *(const uint4*)(Ag + 32);   // tile1 (odd set)
        uint4 sB1 = *(const uint4*)(Bg + 32);
        uint4 sA0 = *(const uint4*)(Ag + 64);   // tile2 (even set)
        uint4 sB0 = *(const uint4*)(Bg + 64);
        BARRIER_KEEP_LOADS();                   // tile1/2 loads stay in flight

#define MQ_COMPUTE(kt)                                                        \
        {                                                                     \
            int bo = ((kt) & 1) << 9;                                         \
            f16x8 af0 = *(const f16x8*)&lds[bo + aidx[0]];                    \
            f16x8 af1 = *(const f16x8*)&lds[bo + aidx[1]];                    \
            f16x8 bf0 = *(const f16x8*)&lds[bo + bidx[0]];                    \
            f16x8 bf1 = *(const f16x8*)&lds[bo + bidx[1]];                    \
            acc[0][0] = MFMA16H(af0, bf0, acc[0][0], 0, 0, 0);                \
            acc[0][1] = MFMA16H(af0, bf1, acc[0][1], 0, 0, 0);                \
            acc[1][0] = MFMA16H(af1, bf0, acc[1][0], 0, 0, 0);                \
            acc[1][1] = MFMA16H(af1, bf1, acc[1][1], 0, 0, 0);                \
        }

        for (int kp = 0; kp < 12; ++kp) {
            int kt = 2 * kp;
            MQ_COMPUTE(kt)
            {
                int bo2 = (((kt) & 1) << 9) ^ 512;
                lds[bo2 + wi] = sA1;             // compiler waits only set1's loads
                lds[bo2 + 256 + wi] = sB1;
                if (kt + 3 < 24) {
                    sA1 = *(const uint4*)(Ag + (kt + 3) * 32);
                    sB1 = *(const uint4*)(Bg + (kt + 3) * 32);
                }
                BARRIER_KEEP_LOADS();            // set0/set1 prefetch stays in flight
            }
            kt = 2 * kp + 1;
            MQ_COMPUTE(kt)
            if (kt < 23) {
                int bo2 = (((kt) & 1) << 9) ^ 512;
                lds[bo2 + wi] = sA0;
                lds[bo2 + 256 + wi] = sB0;
                if (kt + 3 < 24) {
                    sA0 = *(const uint4*)(Ag + (kt + 3) * 32);
                    sB0 = *(const uint4*)(Bg + (kt + 3) * 32);
                }
                BARRIER_KEEP_LOADS();
            }
        }
#undef MQ_COMPUTE

#pragma unroll
        for (int mi = 0; mi < 2; ++mi)
#pragma unroll
            for (int ni = 0; ni < 2; ++ni) {
                int n = n0 + wc * 32 + ni * 16 + lm;
                float bn = bias[n];
                int h = n >> 6, d = n & 63;
                int mbase = m0 + wr * 32 + mi * 16 + hi * 4;
                int bb = mbase >> 9, l0 = mbase & 511;
                if (z == 2) {
                    union { pk16 h2[2]; uint2 u2; } o;
                    o.h2[0] = __builtin_amdgcn_cvt_pkrtz(acc[mi][ni][0] + bn, acc[mi][ni][1] + bn);
                    o.h2[1] = __builtin_amdgcn_cvt_pkrtz(acc[mi][ni][2] + bn, acc[mi][ni][3] + bn);
                    *reinterpret_cast<uint2*>(out + (((bb * NH + h) * HD) + d) * SEQ + l0) = o.u2;
                } else {
#pragma unroll
                    for (int r = 0; r < 4; ++r)
                        out[(((bb * NH + h) * SEQ) + l0 + r) * HD + d] = (f16)(acc[mi][ni][r] + bn);
                }
            }
    } else {
        // ---------- interp role: bilinear bias, 1 pair per thread ----------
        int p = (xcd * 128 + slot) * 256 + t;
        int qi = p >> 9, ki = p & 511;
        float dx = a.qc[2 * qi] - a.kc[2 * ki];
        float dy = a.qc[2 * qi + 1] - a.kc[2 * ki + 1];
        float fxf = __builtin_amdgcn_fmed3f(__builtin_fmaf(dx, 8.f, 80.f), 0.f, 159.9999f);
        float fyf = __builtin_amdgcn_fmed3f(__builtin_fmaf(dy, 8.f, 80.f), 0.f, 159.9999f);
        int ix = (int)fxf, iy = (int)fyf;
        float fx = fxf - (float)ix, fy = fyf - (float)iy;
        const f16* c00 = a.grid16 + (iy * GN + ix) * 16;
        f16x8 g00 = *(const f16x8*)(c00);
        f16x8 g00b = *(const f16x8*)(c00 + 8);
        f16x8 g01 = *(const f16x8*)(c00 + 16);
        f16x8 g01b = *(const f16x8*)(c00 + 24);
        f16x8 g10 = *(const f16x8*)(c00 + GN * 16);
        f16x8 g10b = *(const f16x8*)(c00 + GN * 16 + 8);
        f16x8 g11 = *(const f16x8*)(c00 + GN * 16 + 16);
        f16x8 g11b = *(const f16x8*)(c00 + GN * 16 + 24);
        float o[12];
#pragma unroll
        for (int h = 0; h < 12; ++h) {
            float v00 = (float)(h < 8 ? g00[h] : g00b[h - 8]);
            float v01 = (float)(h < 8 ? g01[h] : g01b[h - 8]);
            float v10 = (float)(h < 8 ? g10[h] : g10b[h - 8]);
            float v11 = (float)(h < 8 ? g11[h] : g11b[h - 8]);
            float v0 = __builtin_fmaf(fx, v01 - v00, v00);
            float v1 = __builtin_fmaf(fx, v11 - v10, v10);
            o[h] = __builtin_fmaf(fy, v1 - v0, v0);
        }
#pragma unroll
        for (int h = 0; h < 12; ++h)
            a.bias16[h * (SEQ * SEQ) + p] = (f16)o[h];
    }
}

// ---------------- O-proj GEMM: 64x64 tile, depth-3 prefetch, raw barriers ----------------
__global__ void __launch_bounds__(256) k_gemmO3(const f16* __restrict__ X,
                                                const f16* __restrict__ WT,
                                                const float* __restrict__ bias,
                                                float* __restrict__ out) {
    __shared__ uint4 lds[1024];
    int bid = blockIdx.x, t = threadIdx.x;
    int lane = t & 63, w = t >> 6;
    int hi = lane >> 4, lm = lane & 15;
    int xcd = bid & 7, slot = bid >> 3;
    int lid = xcd * 96 + slot;
    int m_group = lid / 12, n_tile = lid % 12;
    int m0 = m_group * 64, n0 = n_tile * 64;

    int wr = w >> 1, wc = w & 1;
    int srow = t >> 2, sslot = t & 3;
    const f16* Ag = X + (m0 + srow) * DIM + sslot * 8;
    const f16* Bg = WT + (n0 + srow) * DIM + sslot * 8;
    int wi = srow * 4 + (sslot ^ ((srow >> 1) & 3));

    int aidx[2], bidx[2];
#pragma unroll
    for (int i = 0; i < 2; ++i) {
        int ar = wr * 32 + i * 16 + lm;
        aidx[i] = ar * 4 + (hi ^ ((ar >> 1) & 3));
        int br = wc * 32 + i * 16 + lm;
        bidx[i] = 256 + br * 4 + (hi ^ ((br >> 1) & 3));
    }

    f32x4 acc[2][2] = {};
    {
        uint4 a0 = *(const uint4*)(Ag);
        uint4 b0 = *(const uint4*)(Bg);
        lds[wi] = a0;
        lds[256 + wi] = b0;
    }
    uint4 sA1 = *(const uint4*)(Ag + 32);
    uint4 sB1 = *(const uint4*)(Bg + 32);
    uint4 sA0 = *(const uint4*)(Ag + 64);
    uint4 sB0 = *(const uint4*)(Bg + 64);
    BARRIER_KEEP_LOADS();

#define GO_COMPUTE(kt)                                                        \
    {                                                                         \
        int bo = ((kt) & 1) << 9;                                             \
        f16x8 af0 = *(const f16x8*)&lds[bo + aidx[0]];                        \
        f16x8 af1 = *(const f16x8*)&lds[bo + aidx[1]];                        \
        f16x8 bf0 = *(const f16x8*)&lds[bo + bidx[0]];                        \
        f16x8 bf1 = *(const f16x8*)&lds[bo + bidx[1]];                        \
        acc[0][0] = MFMA16H(af0, bf0, acc[0][0], 0, 0, 0);                    \
        acc[0][1] = MFMA16H(af0, bf1, acc[0][1], 0, 0, 0);                    \
        acc[1][0] = MFMA16H(af1, bf0, acc[1][0], 0, 0, 0);                    \
        acc[1][1] = MFMA16H(af1, bf1, acc[1][1], 0, 0, 0);                    \
    }

    for (int kp = 0; kp < 12; ++kp) {
        int kt = 2 * kp;
        GO_COMPUTE(kt)
        {
            int bo2 = (((kt) & 1) << 9) ^ 512;
            lds[bo2 + wi] = sA1;
            lds[bo2 + 256 + wi] = sB1;
            if (kt + 3 < 24) {
                sA1 = *(const uint4*)(Ag + (kt + 3) * 32);
                sB1 = *(const uint4*)(Bg + (kt + 3) * 32);
            }
            BARRIER_KEEP_LOADS();
        }
        kt = 2 * kp + 1;
        GO_COMPUTE(kt)
        if (kt < 23) {
            int bo2 = (((kt) & 1) << 9) ^ 512;
            lds[bo2 + wi] = sA0;
            lds[bo2 + 256 + wi] = sB0;
            if (kt + 3 < 24) {
                sA0 = *(const uint4*)(Ag + (kt + 3) * 32);
                sB0 = *(const uint4*)(Bg + (kt + 3) * 32);
            }
            BARRIER_KEEP_LOADS();
        }
    }
#undef GO_COMPUTE

#pragma unroll
    for (int mi = 0; mi < 2; ++mi)
#pragma unroll
        for (int ni = 0; ni < 2; ++ni) {
            int n = n0 + wc * 32 + ni * 16 + lm;
            float bn = bias[n];
#pragma unroll
            for (int r = 0; r < 4; ++r) {
                int m = m0 + wr * 32 + mi * 16 + hi * 4 + r;
                out[m * DIM + n] = acc[mi][ni][r] + bn;
            }
        }
}

// ---------------- attention: bias pre-staged to LDS, vectorized softmax scans ----------------
__global__ void __launch_bounds__(256) k_attn8(const f16* __restrict__ q_ws,
                                               const f16* __restrict__ k_ws,
                                               const f16* __restrict__ v_t,
                                               const f16* __restrict__ bias16,
                                               f16* __restrict__ attn_out) {
    __shared__ __align__(16) unsigned short sm16[32 * 520];  // f16 logits [32][520]
    __shared__ float inv32[32];
    int bid = blockIdx.x;
    int xcd = bid & 7, slot = bid >> 3;
    int G = xcd * 12 + (slot >> 4);
    int h = G >> 3, b = G & 7;
    int qt = slot & 15;
    int q0 = qt * 32;
    int t = threadIdx.x, lane = t & 63, w = t >> 6;
    int lrow = lane & 15, hi = lane >> 4;
    int bh = b * NH + h;
    const f16* Q = q_ws + (bh * SEQ + q0) * HD;
    const f16* K = k_ws + bh * SEQ * HD;
    const f16* Bias = bias16 + (h * SEQ + q0) * SEQ;

    // pre-stage bias slice [32][512] into sm16 with coalesced uint4 loads
#pragma unroll
    for (int i = 0; i < 8; ++i) {
        int f = i * 256 + t;
        int row = f >> 6, col8 = f & 63;
        uint4 v = *(const uint4*)&Bias[row * SEQ + col8 * 8];
        *(uint4*)&sm16[row * 520 + col8 * 8] = v;
    }

    f16x8 aq[2][2];
#pragma unroll
    for (int rt = 0; rt < 2; ++rt)
#pragma unroll
        for (int ds = 0; ds < 2; ++ds) {
            f16x8 v = *(const f16x8*)(Q + (rt * 16 + lrow) * HD + ds * 32 + hi * 8);
            aq[rt][ds] = v * (f16)SCALE;   // exact (pow2)
        }
    __syncthreads();

    // phase A: S = (Q*SCALE)K^T + bias(LDS) -> f16 LDS
#pragma unroll
    for (int ct = 0; ct < 8; ++ct) {
        f32x4 acc0 = {}, acc1 = {};
        int kk = w * 128 + ct * 16 + lrow;
#pragma unroll
        for (int ds = 0; ds < 2; ++ds) {
            f16x8 bk = *(const f16x8*)(K + kk * HD + ds * 32 + hi * 8);
            acc0 = MFMA16H(aq[0][ds], bk, acc0, 0, 0, 0);
            acc1 = MFMA16H(aq[1][ds], bk, acc1, 0, 0, 0);
        }
#pragma unroll
        for (int r = 0; r < 4; ++r) {
            int row0 = hi * 4 + r;
            float b0v = (float)*(const f16*)&sm16[row0 * 520 + kk];
            sm16[row0 * 520 + kk] = (unsigned short)__builtin_bit_cast(unsigned short,
                (f16)(acc0[r] + b0v));
            int row1 = 16 + hi * 4 + r;
            float b1v = (float)*(const f16*)&sm16[row1 * 520 + kk];
            sm16[row1 * 520 + kk] = (unsigned short)__builtin_bit_cast(unsigned short,
                (f16)(acc1[r] + b1v));
        }
    }
    __syncthreads();

    // phase B: row softmax, 8 lanes/row, uint4 (8 f16) per scan step
    {
        int row = t >> 3, seg = t & 7;
        int base = row * 520 + seg * 8;
        float mx = -1e30f;
#pragma unroll
        for (int j = 0; j < 8; ++j) {
            union { uint4 u; f16 hh[8]; } cv;
            cv.u = *(const uint4*)&sm16[base + 64 * j];
            float m0 = fmaxf((float)cv.hh[0], (float)cv.hh[1]);
            float m1 = fmaxf((float)cv.hh[2], (float)cv.hh[3]);
            float m2 = fmaxf((float)cv.hh[4], (float)cv.hh[5]);
            float m3 = fmaxf((float)cv.hh[6], (float)cv.hh[7]);
            mx = fmaxf(mx, fmaxf(fmaxf(m0, m1), fmaxf(m2, m3)));
        }
        mx = fmaxf(mx, __shfl_xor(mx, 1));
        mx = fmaxf(mx, __shfl_xor(mx, 2));
        mx = fmaxf(mx, __shfl_xor(mx, 4));
        float s = 0.f;
#pragma unroll
        for (int j = 0; j < 8; ++j) {
            union { uint4 u; f16 hh[8]; } cv;
            cv.u = *(const uint4*)&sm16[base + 64 * j];
            float p[8];
#pragma unroll
            for (int e = 0; e < 8; ++e) {
                p[e] = __builtin_amdgcn_exp2f(((float)cv.hh[e] - mx) * 1.442695041f);
                s += p[e];
            }
            union { pk16 hh[4]; uint4 u; } o;
            o.hh[0] = __builtin_amdgcn_cvt_pkrtz(p[0], p[1]);
            o.hh[1] = __builtin_amdgcn_cvt_pkrtz(p[2], p[3]);
            o.hh[2] = __builtin_amdgcn_cvt_pkrtz(p[4], p[5]);
            o.hh[3] = __builtin_amdgcn_cvt_pkrtz(p[6], p[7]);
            *(uint4*)&sm16[base + 64 * j] = o.u;
        }
        s += __shfl_xor(s, 1);
        s += __shfl_xor(s, 2);
        s += __shfl_xor(s, 4);
        if (seg == 0) inv32[row] = 1.0f / s;
    }
    __syncthreads();

    // phase C: O = P V
    const f16* Vt = v_t + bh * HD * SEQ + (w * 16 + lrow) * SEQ;
    f32x4 oacc0 = {}, oacc1 = {};
    for (int kt = 0; kt < 16; ++kt) {
        f16x8 bv = *(const f16x8*)(Vt + kt * 32 + hi * 8);
        f16x8 pa0 = *(const f16x8*)&sm16[lrow * 520 + kt * 32 + hi * 8];
        f16x8 pa1 = *(const f16x8*)&sm16[(16 + lrow) * 520 + kt * 32 + hi * 8];
        oacc0 = MFMA16H(pa0, bv, oacc0, 0, 0, 0);
        oacc1 = MFMA16H(pa1, bv, oacc1, 0, 0, 0);
    }
#pragma unroll
    for (int r = 0; r < 4; ++r) {
        int row0 = hi * 4 + r;
        float v0 = oacc0[r] * inv32[row0];
        attn_out[(b * SEQ + q0 + row0) * DIM + h * HD + w * 16 + lrow] = (f16)v0;
        int row1 = 16 + hi * 4 + r;
        float v1 = oacc1[r] * inv32[row1];
        attn_out[(b * SEQ + q0 + row1) * DIM + h * HD + w * 16 + lrow] = (f16)v1;
    }
}

extern "C" void kernel_launch(void* const* d_in, const int* in_sizes, int n_in,
                              void* d_out, int out_size, void* d_ws, size_t ws_size,
                              hipStream_t stream) {
    const float* query     = (const float*)d_in[0];
    const float* key_value = (const float*)d_in[1];
    const float* qc        = (const float*)d_in[2];
    const float* kc        = (const float*)d_in[3];
    const float* Wq        = (const float*)d_in[4];
    const float* bq        = (const float*)d_in[5];
    const float* Wk        = (const float*)d_in[6];
    const float* bk        = (const float*)d_in[7];
    const float* Wv        = (const float*)d_in[8];
    const float* bv        = (const float*)d_in[9];
    const float* Wo        = (const float*)d_in[10];
    const float* bo        = (const float*)d_in[11];
    const float* W1        = (const float*)d_in[12];
    const float* b1        = (const float*)d_in[13];
    const float* W2        = (const float*)d_in[14];
    const float* b2        = (const float*)d_in[15];

    char* ws = (char*)d_ws;
    f16* Xq   = (f16*)(ws + 0);          // reused as attn_out
    f16* Xkv  = (f16*)(ws + 6291456);
    f16* WqT  = (f16*)(ws + 12582912);
    f16* WkT  = (f16*)(ws + 13762560);
    f16* WvT  = (f16*)(ws + 14942208);
    f16* WoT  = (f16*)(ws + 16121856);
    f16* q_ws = (f16*)(ws + 17301504);
    f16* k_ws = (f16*)(ws + 23592960);
    f16* v_t  = (f16*)(ws + 29884416);   // V written directly transposed [b,h,d,l]
    f16* bias16   = (f16*)(ws + 36175872); // 6291456 B
    f16* W1tab    = (f16*)(ws + 42467328);
    f16* W2tab    = (f16*)(ws + 42516480);
    float* gtab32 = (float*)(ws + 42541056); // 16384 B
    f16* grid16   = (f16*)(ws + 42557440);   // 829472 B
    f16* attn_out = Xq;   // Xq dead after Q projection

    PrepArgs pa;
    pa.query = query; pa.key_value = key_value; pa.Xq = Xq; pa.Xkv = Xkv;
    pa.W[0] = Wq; pa.W[1] = Wk; pa.W[2] = Wv; pa.W[3] = Wo;
    pa.WT[0] = WqT; pa.WT[1] = WkT; pa.WT[2] = WvT; pa.WT[3] = WoT;
    pa.W1 = W1; pa.b1 = b1; pa.W2 = W2;
    pa.W1tab = W1tab; pa.W2tab = W2tab; pa.gtab32 = gtab32;
    k_prep<<<dim3(5410), dim3(256), 0, stream>>>(pa);

    k_grid<<<dim3(406), dim3(256), 0, stream>>>((const f16x8*)W1tab, (const f16x8*)W2tab,
                                                b2, gtab32, grid16);

    MQArgs mq;
    mq.qc = qc; mq.kc = kc;
    mq.grid16 = grid16; mq.bias16 = bias16;
    mq.Xq = Xq; mq.Xkv = Xkv;
    mq.WqT = WqT; mq.WkT = WkT; mq.WvT = WvT;
    mq.bq = bq; mq.bk = bk; mq.bv = bv;
    mq.q_ws = q_ws; mq.k_ws = k_ws; mq.v_t = v_t;
    k_mq9<<<dim3(3328), dim3(256), 0, stream>>>(mq);

    k_attn8<<<dim3(1536), dim3(256), 0, stream>>>(q_ws, k_ws, v_t, bias16, attn_out);
    k_gemmO3<<<dim3(768), dim3(256), 0, stream>>>(attn_out, WoT, bo, (float*)d_out);
}